// Round 17
// baseline (3765.855 us; speedup 1.0000x reference)
//
#include <hip/hip_runtime.h>

using short8 = __attribute__((ext_vector_type(8))) short;
using f32x4  = __attribute__((ext_vector_type(4))) float;
using uint4v = __attribute__((ext_vector_type(4))) unsigned;

#define NT     512
#define NBATCH 64
#define NN     1024
#define NIN    24
#define NG     8                      // groups of 8 batches
#define ROWS   8
#define TILE32 (ROWS * NN)            // u32 per group tile (32 KB)
#define PARSTRIDE (NG * TILE32)       // u32 per parity buffer (256 KB)
#define SCOPE_AGENT __HIP_MEMORY_SCOPE_AGENT
#define RETRY_CAP (1 << 17)           // fail loud (absmax), never hang

// Epoch-in-data sync (R13-proven) + K-split (R15: wave owns K-slice, W frags
// group-independent) + two-group phase pipeline (R16): block serves gA and gB
// alternately so each group's publish->L3-visibility hides under the other
// group's validate+compute. No flags, no fences, no cache-maintenance ops.

__device__ __forceinline__ unsigned short f2bf(float x) {
  union { float f; unsigned u; } v; v.f = x;
  return (unsigned short)((v.u + 0x7FFFu + ((v.u >> 16) & 1u)) >> 16);
}
__device__ __forceinline__ f32x4 MF(short8 a, short8 b, f32x4 c) {
  return __builtin_amdgcn_mfma_f32_16x16x32_bf16(a, b, c, 0, 0, 0);
}

#define PACKS8(dst, Rx, Ry) do { \
  union { unsigned u[4]; short8 s; } pk_; \
  pk_.u[0] = (Rx[0] & 0xFFFFu) | (Rx[1] << 16); \
  pk_.u[1] = (Rx[2] & 0xFFFFu) | (Rx[3] << 16); \
  pk_.u[2] = (Ry[0] & 0xFFFFu) | (Ry[1] << 16); \
  pk_.u[3] = (Ry[2] & 0xFFFFu) | (Ry[3] << 16); \
  dst = pk_.s; } while (0)

// 32 blocks x 512 thr (8 waves). slot = bid>>2 owns neurons [128*slot,+128);
// wave w = K-slice [128w,+128) for partials, owns output col-set w.
// Pair p = bid&3 serves groups gA=p (batches [8p,+8)) and gB=p+4.
__global__ __launch_bounds__(512, 1) void rnn_step_all(
    const float* __restrict__ u, const float* __restrict__ r0,
    const float* __restrict__ W, const float* __restrict__ Bm,
    const float* __restrict__ tau, const float* __restrict__ ds,
    float* __restrict__ out, unsigned* __restrict__ obs32)
{
  __shared__ f32x4 pl[2][64][32];   // 2 x 32 KB partial tiles (valid rows 0-7)

  const int tid  = threadIdx.x;
  const int wave = tid >> 6;
  const int lane = tid & 63;
  const int bid  = blockIdx.x;
  const int gA   = bid & 3, gB = gA + 4;
  const int slot = bid >> 2;
  const int b0A  = gA * ROWS, b0B = gB * ROWS;
  const int lr = lane & 15, lg = lane >> 4;
  const int i  = slot * 128 + wave * 16 + lr;   // OUTPUT neuron (col-set = wave)

  // ---- W fragments: 8 col-sets x this wave's K-slice (group-independent) ----
  short8 wf[8][4];
#pragma unroll
  for (int c = 0; c < 8; ++c) {
#pragma unroll
    for (int j = 0; j < 4; ++j) {
      const int col = slot * 128 + c * 16 + lr;
      const int k0  = wave * 128 + j * 32 + lg * 8;
      f32x4 w0 = *(const f32x4*)(W + (size_t)col * NN + k0);
      f32x4 w1 = *(const f32x4*)(W + (size_t)col * NN + k0 + 4);
      f32x4 s0 = *(const f32x4*)(ds + k0);
      f32x4 s1 = *(const f32x4*)(ds + k0 + 4);
      short8 f;
      f[0]=(short)f2bf(w0[0]*s0[0]); f[1]=(short)f2bf(w0[1]*s0[1]);
      f[2]=(short)f2bf(w0[2]*s0[2]); f[3]=(short)f2bf(w0[3]*s0[3]);
      f[4]=(short)f2bf(w1[0]*s1[0]); f[5]=(short)f2bf(w1[1]*s1[1]);
      f[6]=(short)f2bf(w1[2]*s1[2]); f[7]=(short)f2bf(w1[3]*s1[3]);
      wf[c][j] = f;
    }
  }
  short8 bin;
#pragma unroll
  for (int e = 0; e < 8; ++e) {
    const int m = lg * 8 + e;
    bin[e] = (short)f2bf(m < NIN ? Bm[(size_t)i * NIN + m] : 0.0f);
  }
  const float itau = 1.0f / tau[i];

  unsigned* gtA0 = obs32 + gA * TILE32;
  unsigned* gtA1 = gtA0 + PARSTRIDE;
  unsigned* gtB0 = obs32 + gB * TILE32;
  unsigned* gtB1 = gtB0 + PARSTRIDE;

  // ---- init r (rows 0-7 live in lg<2 lanes); publish tag 1 into parity 0 ----
  f32x4 rA = {0,0,0,0}, rB = {0,0,0,0};
  if (lg < 2) {
#pragma unroll
    for (int q = 0; q < 4; ++q) {
      const int row = lg * 4 + q;
      rA[q] = r0[(size_t)(b0A + row) * NN + i];
      rB[q] = r0[(size_t)(b0B + row) * NN + i];
      __hip_atomic_store(&gtA0[row * NN + i],
                         (unsigned)f2bf(fmaxf(rA[q], 0.f)) | (1u << 16),
                         __ATOMIC_RELAXED, SCOPE_AGENT);
      __hip_atomic_store(&gtB0[row * NN + i],
                         (unsigned)f2bf(fmaxf(rB[q], 0.f)) | (1u << 16),
                         __ATOMIC_RELAXED, SCOPE_AGENT);
    }
  }

  const float* ubA = u + (size_t)(b0A + (lr & 7)) * NT * NIN;
  const float* ubB = u + (size_t)(b0B + (lr & 7)) * NT * NIN;
  f32x4 uA0={0,0,0,0}, uA1={0,0,0,0}, uB0={0,0,0,0}, uB1={0,0,0,0};
  if (lr < 8 && lg < 3) {
    uA0 = *(const f32x4*)(ubA + lg * 8); uA1 = *(const f32x4*)(ubA + lg * 8 + 4);
    uB0 = *(const f32x4*)(ubB + lg * 8); uB1 = *(const f32x4*)(ubB + lg * 8 + 4);
  }

  for (int t = 0; t < NT; ++t) {
    const unsigned tag  = (unsigned)(t + 1);
    const unsigned tag2 = (unsigned)(t + 2);
    const bool last = (t == NT - 1);

#define PHASE(PP, GT0, GT1, RST, U0, U1, UB, B0) do {                          \
    unsigned* rdt_ = (t & 1) ? (GT1) : (GT0);                                  \
    unsigned* wrt_ = (t & 1) ? (GT0) : (GT1);                                  \
    short8 af0, af1, af2, af3;                                                 \
    { const unsigned* gp = rdt_ + (lr & 7) * NN + wave * 128 + lg * 8;         \
      uint4v R0,R1,R2,R3,R4,R5,R6,R7; int guard = 0;                           \
      for (;;) {                                                               \
        asm volatile(                                                          \
            "global_load_dwordx4 %0, %8, off sc0 sc1\n\t"                      \
            "global_load_dwordx4 %1, %8, off offset:16 sc0 sc1\n\t"            \
            "global_load_dwordx4 %2, %8, off offset:128 sc0 sc1\n\t"           \
            "global_load_dwordx4 %3, %8, off offset:144 sc0 sc1\n\t"           \
            "global_load_dwordx4 %4, %8, off offset:256 sc0 sc1\n\t"           \
            "global_load_dwordx4 %5, %8, off offset:272 sc0 sc1\n\t"           \
            "global_load_dwordx4 %6, %8, off offset:384 sc0 sc1\n\t"           \
            "global_load_dwordx4 %7, %8, off offset:400 sc0 sc1\n\t"           \
            "s_waitcnt vmcnt(0)"                                               \
            : "=&v"(R0), "=&v"(R1), "=&v"(R2), "=&v"(R3),                      \
              "=&v"(R4), "=&v"(R5), "=&v"(R6), "=&v"(R7)                      \
            : "v"(gp) : "memory");                                             \
        unsigned bad = 0;                                                      \
        bad |= ((R0[0]>>16)^tag)|((R0[1]>>16)^tag)|((R0[2]>>16)^tag)|((R0[3]>>16)^tag); \
        bad |= ((R1[0]>>16)^tag)|((R1[1]>>16)^tag)|((R1[2]>>16)^tag)|((R1[3]>>16)^tag); \
        bad |= ((R2[0]>>16)^tag)|((R2[1]>>16)^tag)|((R2[2]>>16)^tag)|((R2[3]>>16)^tag); \
        bad |= ((R3[0]>>16)^tag)|((R3[1]>>16)^tag)|((R3[2]>>16)^tag)|((R3[3]>>16)^tag); \
        bad |= ((R4[0]>>16)^tag)|((R4[1]>>16)^tag)|((R4[2]>>16)^tag)|((R4[3]>>16)^tag); \
        bad |= ((R5[0]>>16)^tag)|((R5[1]>>16)^tag)|((R5[2]>>16)^tag)|((R5[3]>>16)^tag); \
        bad |= ((R6[0]>>16)^tag)|((R6[1]>>16)^tag)|((R6[2]>>16)^tag)|((R6[3]>>16)^tag); \
        bad |= ((R7[0]>>16)^tag)|((R7[1]>>16)^tag)|((R7[2]>>16)^tag)|((R7[3]>>16)^tag); \
        if (__all((int)(bad == 0))) break;                                     \
        if (++guard > RETRY_CAP) break;                                        \
      }                                                                        \
      PACKS8(af0, R0, R1); PACKS8(af1, R2, R3);                                \
      PACKS8(af2, R4, R5); PACKS8(af3, R6, R7); }                              \
    _Pragma("unroll")                                                          \
    for (int c = 0; c < 8; ++c) {                                              \
      f32x4 p = {0,0,0,0};                                                     \
      p = MF(af0, wf[c][0], p); p = MF(af1, wf[c][1], p);                      \
      p = MF(af2, wf[c][2], p); p = MF(af3, wf[c][3], p);                      \
      if (lg < 2) pl[PP][c * 8 + wave][lane] = p;                              \
    }                                                                          \
    __syncthreads();                                                           \
    f32x4 acc = {0,0,0,0};                                                     \
    if (lg < 2) {                                                              \
      acc = pl[PP][wave * 8 + 0][lane];                                        \
      _Pragma("unroll")                                                        \
      for (int s = 1; s < 8; ++s) acc += pl[PP][wave * 8 + s][lane];           \
    }                                                                          \
    short8 ua;                                                                 \
    ua[0]=(short)f2bf(U0[0]); ua[1]=(short)f2bf(U0[1]);                        \
    ua[2]=(short)f2bf(U0[2]); ua[3]=(short)f2bf(U0[3]);                        \
    ua[4]=(short)f2bf(U1[0]); ua[5]=(short)f2bf(U1[1]);                        \
    ua[6]=(short)f2bf(U1[2]); ua[7]=(short)f2bf(U1[3]);                        \
    if (lr >= 8 || lg >= 3) ua = short8{0,0,0,0,0,0,0,0};                      \
    acc = MF(ua, bin, acc);                                                    \
    f32x4 rv;                                                                  \
    _Pragma("unroll")                                                          \
    for (int q = 0; q < 4; ++q) {                                              \
      const float act = 60.0f / (1.0f + expf(8.4f - 0.28f * acc[q]));          \
      rv[q] = RST[q] + (0.1f * (act - RST[q])) * itau;                         \
      RST[q] = rv[q];                                                          \
    }                                                                          \
    if (!last) {                                                               \
      if (lg < 2) {                                                            \
        _Pragma("unroll")                                                      \
        for (int q = 0; q < 4; ++q)                                            \
          __hip_atomic_store(&wrt_[(lg * 4 + q) * NN + i],                     \
              (unsigned)f2bf(fmaxf(rv[q], 0.f)) | (tag2 << 16),                \
              __ATOMIC_RELAXED, SCOPE_AGENT);                                  \
      }                                                                        \
      if (lr < 8 && lg < 3) {                                                  \
        const float* up_ = (UB) + (t + 1) * NIN + lg * 8;                      \
        U0 = *(const f32x4*)(up_); U1 = *(const f32x4*)(up_ + 4);              \
      }                                                                        \
    }                                                                          \
    if (lg < 2) {                                                              \
      _Pragma("unroll")                                                        \
      for (int q = 0; q < 4; ++q)                                              \
        out[((size_t)((B0) + lg * 4 + q) * NT + t) * NN + i] = rv[q];          \
    }                                                                          \
  } while (0)

    PHASE(0, gtA0, gtA1, rA, uA0, uA1, ubA, b0A);
    PHASE(1, gtB0, gtB1, rB, uB0, uB1, ubB, b0B);
#undef PHASE
  }

  // r_final (both groups)
  if (lg < 2) {
    const size_t fbase = (size_t)NBATCH * NT * NN;
#pragma unroll
    for (int q = 0; q < 4; ++q) {
      const int row = lg * 4 + q;
      out[fbase + (size_t)(b0A + row) * NN + i] = rA[q];
      out[fbase + (size_t)(b0B + row) * NN + i] = rB[q];
    }
  }
}

extern "C" void kernel_launch(void* const* d_in, const int* in_sizes, int n_in,
                              void* d_out, int out_size, void* d_ws, size_t ws_size,
                              hipStream_t stream) {
  const float* u   = (const float*)d_in[0];
  const float* r0  = (const float*)d_in[1];
  const float* W   = (const float*)d_in[2];
  const float* Bm  = (const float*)d_in[3];
  const float* tau = (const float*)d_in[4];
  const float* ds  = (const float*)d_in[5];
  float* out = (float*)d_out;

  unsigned* obs32 = (unsigned*)d_ws;

  // zero both epoch-tagged buffers every call (tags restart at 1 -> deterministic)
  hipMemsetAsync(d_ws, 0, 2 * PARSTRIDE * sizeof(unsigned), stream);

  rnn_step_all<<<dim3(32), dim3(512), 0, stream>>>(u, r0, W, Bm, tau, ds,
                                                   out, obs32);
}